// Round 1
// baseline (770.466 us; speedup 1.0000x reference)
//
#include <hip/hip_runtime.h>
#include <stdint.h>

typedef float vfloat4 __attribute__((ext_vector_type(4)));
typedef float vfloat2 __attribute__((ext_vector_type(2)));

// B=1024, N=8192, D=128
// out layout (floats): quantized[1024][1024][128] | ind[1024] | loss[1]
static const long long QN       = 134217728LL;
static const long long IND_OFF  = QN;
static const long long LOSS_OFF = QN + 1024;

// ws layout (float offsets). ws is 2 GiB; we use ~1.1 MB.
#define WS_W2    0        // 8192 floats
#define WS_X2    8192     // 1024
#define WS_SX    9216     // 128
#define WS_IND   9344     // 1024 ints (bit-stored)
#define WS_PVAL  16384    // 65536 floats (1024 x 64)
#define WS_PIDX  81920    // 65536 ints
#define WS_Q     147456   // 131072 floats (1024 x 128 gathered codes)

// Fused prep: blocks 0-31 w2 rows; 32-35 x2 rows; 36-39 x column-sums
// (each block owns 32 columns — no atomics).
__global__ __launch_bounds__(256) void k_prep(const float* __restrict__ x,
                                              const float* __restrict__ W,
                                              float* __restrict__ ws) {
    const int b = blockIdx.x, tid = threadIdx.x;
    if (b < 36) {
        const float4* pr = (b < 32) ? ((const float4*)W + (size_t)(b * 256 + tid) * 32)
                                    : ((const float4*)x + (size_t)((b - 32) * 256 + tid) * 32);
        float s = 0.0f;
#pragma unroll 8
        for (int t = 0; t < 32; ++t) {
            float4 v = pr[t];
            s += v.x * v.x + v.y * v.y + v.z * v.z + v.w * v.w;
        }
        if (b < 32) ws[WS_W2 + b * 256 + tid] = s;
        else        ws[WS_X2 + (b - 32) * 256 + tid] = s;
    } else {
        __shared__ float sh[8][32];
        const int c = tid & 31, g = tid >> 5;
        const int col = (b - 36) * 32 + c;
        float sum = 0.0f;
        for (int r = g; r < 1024; r += 8) sum += x[(size_t)r * 128 + col];
        sh[g][c] = sum;
        __syncthreads();
        if (g == 0) {
            float t = 0.0f;
#pragma unroll
            for (int gg = 0; gg < 8; ++gg) t += sh[gg][c];
            ws[WS_SX + col] = t;
        }
    }
}

// dist[m][n] with the reference's fp32 rounding:
//   t = x2[m] - 2*dot(x_m,W_n); s = t + w2[n]
// Per-block partial argmin (first-occurrence tie-break) over a 128-col chunk.
// Numerics path verified in a prior round — accumulation is fused-FMA per
// acc element in identical k-order; v_pk_fma_f32 packs two such chains per
// instruction (bit-identical results, half the VALU instruction count).
#define ACC(i, j) acc[i][(j) >> 1][(j) & 1]
__global__ __launch_bounds__(256) void k_score(
    const float* __restrict__ x, const float* __restrict__ W,
    const float* __restrict__ w2, const float* __restrict__ x2,
    float* __restrict__ pval, int* __restrict__ pidx) {
    __shared__ float Xs[32][132];  // [k][m], +4 pad
    __shared__ float Wst[32][132]; // [k][n]
    const int tid = threadIdx.x;
    const int tx = tid & 15, ty = tid >> 4;
    const int n0 = blockIdx.x * 128, m0 = blockIdx.y * 128;
    const float4* xv = (const float4*)x;
    const float4* wv = (const float4*)W;

    vfloat2 acc[8][4];
#pragma unroll
    for (int i = 0; i < 8; ++i)
#pragma unroll
        for (int jp = 0; jp < 4; ++jp) acc[i][jp] = (vfloat2)(0.0f);

    for (int kc = 0; kc < 4; ++kc) {
#pragma unroll
        for (int it = 0; it < 4; ++it) {
            int f = it * 256 + tid;
            int m = f >> 3, kq = f & 7;
            float4 a = xv[(size_t)(m0 + m) * 32 + kc * 8 + kq];
            float4 b = wv[(size_t)(n0 + m) * 32 + kc * 8 + kq];
            Xs[kq * 4 + 0][m] = a.x;
            Xs[kq * 4 + 1][m] = a.y;
            Xs[kq * 4 + 2][m] = a.z;
            Xs[kq * 4 + 3][m] = a.w;
            Wst[kq * 4 + 0][m] = b.x;
            Wst[kq * 4 + 1][m] = b.y;
            Wst[kq * 4 + 2][m] = b.z;
            Wst[kq * 4 + 3][m] = b.w;
        }
        __syncthreads();
#pragma unroll 8
        for (int k = 0; k < 32; ++k) {
            float4 a0 = *(const float4*)&Xs[k][ty * 8];
            float4 a1 = *(const float4*)&Xs[k][ty * 8 + 4];
            float4 b0 = *(const float4*)&Wst[k][tx * 8];
            float4 b1 = *(const float4*)&Wst[k][tx * 8 + 4];
            float af[8] = {a0.x, a0.y, a0.z, a0.w, a1.x, a1.y, a1.z, a1.w};
            vfloat2 bb[4];
            bb[0][0] = b0.x; bb[0][1] = b0.y;
            bb[1][0] = b0.z; bb[1][1] = b0.w;
            bb[2][0] = b1.x; bb[2][1] = b1.y;
            bb[3][0] = b1.z; bb[3][1] = b1.w;
#pragma unroll
            for (int i = 0; i < 8; ++i) {
                vfloat2 av;
                av[0] = af[i]; av[1] = af[i];
#pragma unroll
                for (int jp = 0; jp < 4; ++jp)
                    acc[i][jp] = __builtin_elementwise_fma(av, bb[jp], acc[i][jp]);
            }
        }
        __syncthreads();
    }

    float w2v[8];
#pragma unroll
    for (int j = 0; j < 8; ++j) w2v[j] = w2[n0 + tx * 8 + j];

#pragma unroll
    for (int i = 0; i < 8; ++i) {
        const int row = m0 + ty * 8 + i;
        const float xxv = x2[row];
        float bestv;
        int besti = n0 + tx * 8;
        {
            float t = xxv - 2.0f * ACC(i, 0);
            bestv = t + w2v[0];
        }
#pragma unroll
        for (int j = 1; j < 8; ++j) {
            float t = xxv - 2.0f * ACC(i, j);
            float s = t + w2v[j];
            if (s < bestv) { bestv = s; besti = n0 + tx * 8 + j; }
        }
        for (int off = 1; off < 16; off <<= 1) {
            float ov = __shfl_xor(bestv, off, 64);
            int oi = __shfl_xor(besti, off, 64);
            if (ov < bestv || (ov == bestv && oi < besti)) { bestv = ov; besti = oi; }
        }
        if (tx == 0) {
            pval[row * 64 + blockIdx.x] = bestv;
            pidx[row * 64 + blockIdx.x] = besti;
        }
    }
}

// Final argmin: 512 blocks x 128 threads, one wave per row (2 rows/block).
// Butterfly min with (val, min-idx) tie-break == first-occurrence scan, since
// pidx from column-chunk c only contains indices in [c*128, c*128+128).
// Lane 0 writes ind (float) + int copy to ws; lanes 0-31 gather the code row.
__global__ __launch_bounds__(128) void k_argmin(
    const float* __restrict__ W,
    const float* __restrict__ pval, const int* __restrict__ pidx,
    float* __restrict__ out, float* __restrict__ ws) {
    const int tid = threadIdx.x;
    const int w = tid >> 6, lane = tid & 63;
    const int r = blockIdx.x * 2 + w;
    float bestv = pval[r * 64 + lane];
    int besti = pidx[r * 64 + lane];
    for (int off = 1; off < 64; off <<= 1) {
        float ov = __shfl_xor(bestv, off, 64);
        int oi = __shfl_xor(besti, off, 64);
        if (ov < bestv || (ov == bestv && oi < besti)) { bestv = ov; besti = oi; }
    }
    if (lane == 0) {
        out[IND_OFF + r] = (float)besti;
        ((int*)ws)[WS_IND + r] = besti;
    }
    if (lane < 32) {
        const float4* wv = (const float4*)W;
        float4* wsq = (float4*)(ws + WS_Q);
        wsq[(size_t)r * 32 + lane] = wv[(size_t)besti * 32 + lane];
    }
}

// quantized[i][j][:] = q[i]. 537 MB stream write; block 0 computes the loss
// scalar (sq column sums over the gathered q, Sq2 = sum w2[ind], Sx2, dot with
// sx) while blocks 1..2048 each stream 4 x 64 KB chunks. The ~7 us loss path
// hides entirely under the ~86 us write stream.
__global__ __launch_bounds__(256) void k_bcast(float* __restrict__ out,
                                               const float* __restrict__ ws) {
    const int bid = blockIdx.x, tid = threadIdx.x;
    if (bid == 0) {
        __shared__ float shq[2][128];
        __shared__ float sh[256];
        const int d = tid & 127, g = tid >> 7;
        float s = 0.0f;
        for (int r = g; r < 1024; r += 2) s += ws[WS_Q + (size_t)r * 128 + d];
        shq[g][d] = s;
        __syncthreads();
        float dotv = 0.0f;
        if (tid < 128) dotv = (shq[0][tid] + shq[1][tid]) * ws[WS_SX + tid];
        float sx2 = 0.0f;
        for (int r = tid; r < 1024; r += 256) sx2 += ws[WS_X2 + r];
        const int* wsI = (const int*)ws + WS_IND;
        float sq2 = 0.0f;
        for (int r = tid; r < 1024; r += 256) sq2 += ws[WS_W2 + wsI[r]];
        sh[tid] = dotv;
        __syncthreads();
        for (int st = 128; st > 0; st >>= 1) {
            if (tid < st) sh[tid] += sh[tid + st];
            __syncthreads();
        }
        const float dot = sh[0];
        __syncthreads();
        sh[tid] = sx2;
        __syncthreads();
        for (int st = 128; st > 0; st >>= 1) {
            if (tid < st) sh[tid] += sh[tid + st];
            __syncthreads();
        }
        const float Sx2 = sh[0];
        __syncthreads();
        sh[tid] = sq2;
        __syncthreads();
        for (int st = 128; st > 0; st >>= 1) {
            if (tid < st) sh[tid] += sh[tid + st];
            __syncthreads();
        }
        if (tid == 0) {
            double loss = 1.25 * (1024.0 * (double)Sx2 + 1024.0 * (double)sh[0] - 2.0 * (double)dot) / 134217728.0;
            out[LOSS_OFF] = (float)loss;
        }
        return;
    }
    const int c0 = (bid - 1) * 4;
    const int t = tid & 31;
#pragma unroll
    for (int cc = 0; cc < 4; ++cc) {
        const int chunk = c0 + cc;
        const int i = chunk >> 3;       // row 0..1023
        const int e = chunk & 7;        // eighth of the j range
        const vfloat4* src = (const vfloat4*)(ws + WS_Q) + (size_t)i * 32;
        vfloat4 qv = src[t];
        vfloat4* dst = (vfloat4*)out + (size_t)i * 32768 + t;
        const int jend = e * 128 + 128;
        for (int j = e * 128 + (tid >> 5); j < jend; j += 8) {
            dst[(size_t)j * 32] = qv;
        }
    }
}

extern "C" void kernel_launch(void* const* d_in, const int* in_sizes, int n_in,
                              void* d_out, int out_size, void* d_ws, size_t ws_size,
                              hipStream_t stream) {
    const float* x = (const float*)d_in[0]; // 1024 x 128
    const float* W = (const float*)d_in[1]; // 8192 x 128
    float* out = (float*)d_out;
    float* ws = (float*)d_ws;

    hipLaunchKernelGGL(k_prep, dim3(40), dim3(256), 0, stream, x, W, ws);
    hipLaunchKernelGGL(k_score, dim3(64, 8), dim3(256), 0, stream, x, W,
                       ws + WS_W2, ws + WS_X2, ws + WS_PVAL, (int*)(ws + WS_PIDX));
    hipLaunchKernelGGL(k_argmin, dim3(512), dim3(128), 0, stream, W,
                       ws + WS_PVAL, (const int*)(ws + WS_PIDX), out, ws);
    hipLaunchKernelGGL(k_bcast, dim3(2049), dim3(256), 0, stream, out, ws);
}

// Round 2
// 729.719 us; speedup vs baseline: 1.0558x; 1.0558x over previous
//
#include <hip/hip_runtime.h>
#include <stdint.h>

typedef float vfloat4 __attribute__((ext_vector_type(4)));

// B=1024, N=8192, D=128
// out layout (floats): quantized[1024][1024][128] | ind[1024] | loss[1]
static const long long QN       = 134217728LL;
static const long long IND_OFF  = QN;
static const long long LOSS_OFF = QN + 1024;

// ws layout (float offsets). ws is 2 GiB; we use ~1.1 MB.
#define WS_W2    0        // 8192 floats
#define WS_X2    8192     // 1024
#define WS_SX    9216     // 128
#define WS_IND   9344     // 1024 ints (bit-stored)
#define WS_PVAL  16384    // 65536 floats (1024 x 64)
#define WS_PIDX  81920    // 65536 ints
#define WS_Q     147456   // 131072 floats (1024 x 128 gathered codes)

// Fused prep: blocks 0-31 w2 rows; 32-35 x2 rows; 36-39 x column-sums
// (each block owns 32 columns — no atomics).
__global__ __launch_bounds__(256) void k_prep(const float* __restrict__ x,
                                              const float* __restrict__ W,
                                              float* __restrict__ ws) {
    const int b = blockIdx.x, tid = threadIdx.x;
    if (b < 36) {
        const float4* pr = (b < 32) ? ((const float4*)W + (size_t)(b * 256 + tid) * 32)
                                    : ((const float4*)x + (size_t)((b - 32) * 256 + tid) * 32);
        float s = 0.0f;
#pragma unroll 8
        for (int t = 0; t < 32; ++t) {
            float4 v = pr[t];
            s += v.x * v.x + v.y * v.y + v.z * v.z + v.w * v.w;
        }
        if (b < 32) ws[WS_W2 + b * 256 + tid] = s;
        else        ws[WS_X2 + (b - 32) * 256 + tid] = s;
    } else {
        __shared__ float sh[8][32];
        const int c = tid & 31, g = tid >> 5;
        const int col = (b - 36) * 32 + c;
        float sum = 0.0f;
        for (int r = g; r < 1024; r += 8) sum += x[(size_t)r * 128 + col];
        sh[g][c] = sum;
        __syncthreads();
        if (g == 0) {
            float t = 0.0f;
#pragma unroll
            for (int gg = 0; gg < 8; ++gg) t += sh[gg][c];
            ws[WS_SX + col] = t;
        }
    }
}

// dist[m][n] with the reference's fp32 rounding:
//   t = x2[m] - 2*dot(x_m,W_n); s = t + w2[n]
// Per-block partial argmin (first-occurrence tie-break) over a 128-col chunk.
// VERIFIED CORRECT + known-good codegen (638 us session) — byte-identical
// revert of the round-1 vfloat2 experiment (which regressed ~130 us, most
// likely via aligned-VGPR-pair regalloc damage / occupancy drop).
__global__ __launch_bounds__(256) void k_score(
    const float* __restrict__ x, const float* __restrict__ W,
    const float* __restrict__ w2, const float* __restrict__ x2,
    float* __restrict__ pval, int* __restrict__ pidx) {
    __shared__ float Xs[32][132];  // [k][m], +4 pad
    __shared__ float Wst[32][132]; // [k][n]
    const int tid = threadIdx.x;
    const int tx = tid & 15, ty = tid >> 4;
    const int n0 = blockIdx.x * 128, m0 = blockIdx.y * 128;
    const float4* xv = (const float4*)x;
    const float4* wv = (const float4*)W;

    float acc[8][8];
#pragma unroll
    for (int i = 0; i < 8; ++i)
#pragma unroll
        for (int j = 0; j < 8; ++j) acc[i][j] = 0.0f;

    for (int kc = 0; kc < 4; ++kc) {
#pragma unroll
        for (int it = 0; it < 4; ++it) {
            int f = it * 256 + tid;
            int m = f >> 3, kq = f & 7;
            float4 a = xv[(size_t)(m0 + m) * 32 + kc * 8 + kq];
            float4 b = wv[(size_t)(n0 + m) * 32 + kc * 8 + kq];
            Xs[kq * 4 + 0][m] = a.x;
            Xs[kq * 4 + 1][m] = a.y;
            Xs[kq * 4 + 2][m] = a.z;
            Xs[kq * 4 + 3][m] = a.w;
            Wst[kq * 4 + 0][m] = b.x;
            Wst[kq * 4 + 1][m] = b.y;
            Wst[kq * 4 + 2][m] = b.z;
            Wst[kq * 4 + 3][m] = b.w;
        }
        __syncthreads();
#pragma unroll 8
        for (int k = 0; k < 32; ++k) {
            float4 a0 = *(const float4*)&Xs[k][ty * 8];
            float4 a1 = *(const float4*)&Xs[k][ty * 8 + 4];
            float4 b0 = *(const float4*)&Wst[k][tx * 8];
            float4 b1 = *(const float4*)&Wst[k][tx * 8 + 4];
            float af[8] = {a0.x, a0.y, a0.z, a0.w, a1.x, a1.y, a1.z, a1.w};
            float bf[8] = {b0.x, b0.y, b0.z, b0.w, b1.x, b1.y, b1.z, b1.w};
#pragma unroll
            for (int i = 0; i < 8; ++i)
#pragma unroll
                for (int j = 0; j < 8; ++j) acc[i][j] += af[i] * bf[j];
        }
        __syncthreads();
    }

    float w2v[8];
#pragma unroll
    for (int j = 0; j < 8; ++j) w2v[j] = w2[n0 + tx * 8 + j];

#pragma unroll
    for (int i = 0; i < 8; ++i) {
        const int row = m0 + ty * 8 + i;
        const float xxv = x2[row];
        float bestv;
        int besti = n0 + tx * 8;
        {
            float t = xxv - 2.0f * acc[i][0];
            bestv = t + w2v[0];
        }
#pragma unroll
        for (int j = 1; j < 8; ++j) {
            float t = xxv - 2.0f * acc[i][j];
            float s = t + w2v[j];
            if (s < bestv) { bestv = s; besti = n0 + tx * 8 + j; }
        }
        for (int off = 1; off < 16; off <<= 1) {
            float ov = __shfl_xor(bestv, off, 64);
            int oi = __shfl_xor(besti, off, 64);
            if (ov < bestv || (ov == bestv && oi < besti)) { bestv = ov; besti = oi; }
        }
        if (tx == 0) {
            pval[row * 64 + blockIdx.x] = bestv;
            pidx[row * 64 + blockIdx.x] = besti;
        }
    }
}

// Final argmin: 512 blocks x 128 threads, one wave per row (2 rows/block).
// Butterfly min with (val, min-idx) tie-break == first-occurrence scan, since
// pidx from column-chunk c only contains indices in [c*128, c*128+128).
// Lane 0 writes ind (float) + int copy to ws; lanes 0-31 gather the code row.
__global__ __launch_bounds__(128) void k_argmin(
    const float* __restrict__ W,
    const float* __restrict__ pval, const int* __restrict__ pidx,
    float* __restrict__ out, float* __restrict__ ws) {
    const int tid = threadIdx.x;
    const int w = tid >> 6, lane = tid & 63;
    const int r = blockIdx.x * 2 + w;
    float bestv = pval[r * 64 + lane];
    int besti = pidx[r * 64 + lane];
    for (int off = 1; off < 64; off <<= 1) {
        float ov = __shfl_xor(bestv, off, 64);
        int oi = __shfl_xor(besti, off, 64);
        if (ov < bestv || (ov == bestv && oi < besti)) { bestv = ov; besti = oi; }
    }
    if (lane == 0) {
        out[IND_OFF + r] = (float)besti;
        ((int*)ws)[WS_IND + r] = besti;
    }
    if (lane < 32) {
        const float4* wv = (const float4*)W;
        float4* wsq = (float4*)(ws + WS_Q);
        wsq[(size_t)r * 32 + lane] = wv[(size_t)besti * 32 + lane];
    }
}

// quantized[i][j][:] = q[i]. 537 MB stream write; 8192 blocks x 64 KB
// (round-0 geometry, known-good). Block 0 additionally computes the loss
// scalar first (atomic-free: sq column sums from the gathered q in ws,
// Sq2 = sum w2[ind], Sx2, dot with sx) — hides under the write stream.
__global__ __launch_bounds__(256) void k_bcast(float* __restrict__ out,
                                               const float* __restrict__ ws) {
    const int bid = blockIdx.x, tid = threadIdx.x;
    if (bid == 0) {
        __shared__ float shq[2][128];
        __shared__ float sh[256];
        const int d = tid & 127, g = tid >> 7;
        float s = 0.0f;
        for (int r = g; r < 1024; r += 2) s += ws[WS_Q + (size_t)r * 128 + d];
        shq[g][d] = s;
        __syncthreads();
        float dotv = 0.0f;
        if (tid < 128) dotv = (shq[0][tid] + shq[1][tid]) * ws[WS_SX + tid];
        float sx2 = 0.0f;
        for (int r = tid; r < 1024; r += 256) sx2 += ws[WS_X2 + r];
        const int* wsI = (const int*)ws + WS_IND;
        float sq2 = 0.0f;
        for (int r = tid; r < 1024; r += 256) sq2 += ws[WS_W2 + wsI[r]];
        sh[tid] = dotv;
        __syncthreads();
        for (int st = 128; st > 0; st >>= 1) {
            if (tid < st) sh[tid] += sh[tid + st];
            __syncthreads();
        }
        const float dot = sh[0];
        __syncthreads();
        sh[tid] = sx2;
        __syncthreads();
        for (int st = 128; st > 0; st >>= 1) {
            if (tid < st) sh[tid] += sh[tid + st];
            __syncthreads();
        }
        const float Sx2 = sh[0];
        __syncthreads();
        sh[tid] = sq2;
        __syncthreads();
        for (int st = 128; st > 0; st >>= 1) {
            if (tid < st) sh[tid] += sh[tid + st];
            __syncthreads();
        }
        if (tid == 0) {
            double loss = 1.25 * (1024.0 * (double)Sx2 + 1024.0 * (double)sh[0] - 2.0 * (double)dot) / 134217728.0;
            out[LOSS_OFF] = (float)loss;
        }
        __syncthreads();
    }
    const int i = bid >> 3;          // row 0..1023
    const int e = bid & 7;           // eighth of the j range
    const int t = tid & 31;
    const vfloat4* src = (const vfloat4*)(ws + WS_Q) + (size_t)i * 32;
    vfloat4 qv = src[t];
    vfloat4* dst = (vfloat4*)out + (size_t)i * 32768 + t;
    const int jend = e * 128 + 128;
    for (int j = e * 128 + (tid >> 5); j < jend; j += 8) {
        dst[(size_t)j * 32] = qv;
    }
}

extern "C" void kernel_launch(void* const* d_in, const int* in_sizes, int n_in,
                              void* d_out, int out_size, void* d_ws, size_t ws_size,
                              hipStream_t stream) {
    const float* x = (const float*)d_in[0]; // 1024 x 128
    const float* W = (const float*)d_in[1]; // 8192 x 128
    float* out = (float*)d_out;
    float* ws = (float*)d_ws;

    hipLaunchKernelGGL(k_prep, dim3(40), dim3(256), 0, stream, x, W, ws);
    hipLaunchKernelGGL(k_score, dim3(64, 8), dim3(256), 0, stream, x, W,
                       ws + WS_W2, ws + WS_X2, ws + WS_PVAL, (int*)(ws + WS_PIDX));
    hipLaunchKernelGGL(k_argmin, dim3(512), dim3(128), 0, stream, W,
                       ws + WS_PVAL, (const int*)(ws + WS_PIDX), out, ws);
    hipLaunchKernelGGL(k_bcast, dim3(8192), dim3(256), 0, stream, out, ws);
}

// Round 3
// 622.976 us; speedup vs baseline: 1.2368x; 1.1713x over previous
//
#include <hip/hip_runtime.h>
#include <stdint.h>

typedef float vfloat4 __attribute__((ext_vector_type(4)));

// B=1024, N=8192, D=128
// out layout (floats): quantized[1024][1024][128] | ind[1024] | loss[1]
static const long long QN       = 134217728LL;
static const long long IND_OFF  = QN;
static const long long LOSS_OFF = QN + 1024;

// ws layout (float offsets). ws is 2 GiB; we use ~1.1 MB.
#define WS_W2    0        // 8192 floats
#define WS_X2    8192     // 1024
#define WS_SX    9216     // 128
#define WS_SQ    9344     // 128
#define WS_SQ2   9472     // 1
#define WS_PVAL  16384    // 65536 floats (1024 x 64)
#define WS_PIDX  81920    // 65536 ints
#define WS_Q     147456   // 131072 floats (1024 x 128 gathered codes)

// Fused prep: blocks 0-31 w2 rows; 32-35 x2 rows; 36-39 x column-sums
// (each block owns 32 columns — no atomics) + block 36 zeros sq/Sq2.
// Byte-identical to the 638 us round-0 kernel.
__global__ __launch_bounds__(256) void k_prep(const float* __restrict__ x,
                                              const float* __restrict__ W,
                                              float* __restrict__ ws) {
    const int b = blockIdx.x, tid = threadIdx.x;
    if (b < 36) {
        const float4* pr = (b < 32) ? ((const float4*)W + (size_t)(b * 256 + tid) * 32)
                                    : ((const float4*)x + (size_t)((b - 32) * 256 + tid) * 32);
        float s = 0.0f;
#pragma unroll 8
        for (int t = 0; t < 32; ++t) {
            float4 v = pr[t];
            s += v.x * v.x + v.y * v.y + v.z * v.z + v.w * v.w;
        }
        if (b < 32) ws[WS_W2 + b * 256 + tid] = s;
        else        ws[WS_X2 + (b - 32) * 256 + tid] = s;
    } else {
        __shared__ float sh[8][32];
        const int c = tid & 31, g = tid >> 5;
        const int col = (b - 36) * 32 + c;
        float sum = 0.0f;
        for (int r = g; r < 1024; r += 8) sum += x[(size_t)r * 128 + col];
        sh[g][c] = sum;
        __syncthreads();
        if (g == 0) {
            float t = 0.0f;
#pragma unroll
            for (int gg = 0; gg < 8; ++gg) t += sh[gg][c];
            ws[WS_SX + col] = t;
        }
        if (b == 36 && tid < 129) ws[WS_SQ + tid] = 0.0f; // sq[128] + Sq2
    }
}

// dist[m][n] with the reference's fp32 rounding:
//   t = x2[m] - 2*dot(x_m,W_n); s = t + w2[n]
// Per-block partial argmin (first-occurrence tie-break) over a 128-col chunk.
// VERIFIED CORRECT — byte-identical to the 638 us round-0 kernel.
__global__ __launch_bounds__(256) void k_score(
    const float* __restrict__ x, const float* __restrict__ W,
    const float* __restrict__ w2, const float* __restrict__ x2,
    float* __restrict__ pval, int* __restrict__ pidx) {
    __shared__ float Xs[32][132];  // [k][m], +4 pad
    __shared__ float Wst[32][132]; // [k][n]
    const int tid = threadIdx.x;
    const int tx = tid & 15, ty = tid >> 4;
    const int n0 = blockIdx.x * 128, m0 = blockIdx.y * 128;
    const float4* xv = (const float4*)x;
    const float4* wv = (const float4*)W;

    float acc[8][8];
#pragma unroll
    for (int i = 0; i < 8; ++i)
#pragma unroll
        for (int j = 0; j < 8; ++j) acc[i][j] = 0.0f;

    for (int kc = 0; kc < 4; ++kc) {
#pragma unroll
        for (int it = 0; it < 4; ++it) {
            int f = it * 256 + tid;
            int m = f >> 3, kq = f & 7;
            float4 a = xv[(size_t)(m0 + m) * 32 + kc * 8 + kq];
            float4 b = wv[(size_t)(n0 + m) * 32 + kc * 8 + kq];
            Xs[kq * 4 + 0][m] = a.x;
            Xs[kq * 4 + 1][m] = a.y;
            Xs[kq * 4 + 2][m] = a.z;
            Xs[kq * 4 + 3][m] = a.w;
            Wst[kq * 4 + 0][m] = b.x;
            Wst[kq * 4 + 1][m] = b.y;
            Wst[kq * 4 + 2][m] = b.z;
            Wst[kq * 4 + 3][m] = b.w;
        }
        __syncthreads();
#pragma unroll 8
        for (int k = 0; k < 32; ++k) {
            float4 a0 = *(const float4*)&Xs[k][ty * 8];
            float4 a1 = *(const float4*)&Xs[k][ty * 8 + 4];
            float4 b0 = *(const float4*)&Wst[k][tx * 8];
            float4 b1 = *(const float4*)&Wst[k][tx * 8 + 4];
            float af[8] = {a0.x, a0.y, a0.z, a0.w, a1.x, a1.y, a1.z, a1.w};
            float bf[8] = {b0.x, b0.y, b0.z, b0.w, b1.x, b1.y, b1.z, b1.w};
#pragma unroll
            for (int i = 0; i < 8; ++i)
#pragma unroll
                for (int j = 0; j < 8; ++j) acc[i][j] += af[i] * bf[j];
        }
        __syncthreads();
    }

    float w2v[8];
#pragma unroll
    for (int j = 0; j < 8; ++j) w2v[j] = w2[n0 + tx * 8 + j];

#pragma unroll
    for (int i = 0; i < 8; ++i) {
        const int row = m0 + ty * 8 + i;
        const float xxv = x2[row];
        float bestv;
        int besti = n0 + tx * 8;
        {
            float t = xxv - 2.0f * acc[i][0];
            bestv = t + w2v[0];
        }
#pragma unroll
        for (int j = 1; j < 8; ++j) {
            float t = xxv - 2.0f * acc[i][j];
            float s = t + w2v[j];
            if (s < bestv) { bestv = s; besti = n0 + tx * 8 + j; }
        }
        for (int off = 1; off < 16; off <<= 1) {
            float ov = __shfl_xor(bestv, off, 64);
            int oi = __shfl_xor(besti, off, 64);
            if (ov < bestv || (ov == bestv && oi < besti)) { bestv = ov; besti = oi; }
        }
        if (tx == 0) {
            pval[row * 64 + blockIdx.x] = bestv;
            pidx[row * 64 + blockIdx.x] = besti;
        }
    }
}

// Final argmin per row. Round-0 structure (sq via atomics, Sq2 = w2[ind]),
// but 16 blocks x 64 rows instead of 4 x 256 — the ONLY change this round,
// cutting the 4-CU straggler 4x. Wave-per-row butterfly min with
// (val, min-idx) tie-break == first-occurrence scan, since pidx from
// column-chunk c only contains indices in [c*128, c*128+128).
__global__ __launch_bounds__(256) void k_argmin(
    const float* __restrict__ W, const float* __restrict__ w2,
    const float* __restrict__ pval, const int* __restrict__ pidx,
    float* __restrict__ out, float* __restrict__ ws) {
    __shared__ int sidx[64];
    __shared__ float sh[2][128];
    const int tid = threadIdx.x;
    const int w = tid >> 6, lane = tid & 63;
    const int r0 = blockIdx.x * 64;
    float q2 = 0.0f;
#pragma unroll 4
    for (int it = 0; it < 16; ++it) {
        const int rr = it * 4 + w;       // local row 0..63
        const int r = r0 + rr;
        float bestv = pval[r * 64 + lane];
        int besti = pidx[r * 64 + lane];
        for (int off = 1; off < 64; off <<= 1) {
            float ov = __shfl_xor(bestv, off, 64);
            int oi = __shfl_xor(besti, off, 64);
            if (ov < bestv || (ov == bestv && oi < besti)) { bestv = ov; besti = oi; }
        }
        if (lane == 0) {
            out[IND_OFF + r] = (float)besti;
            sidx[rr] = besti;
            q2 += w2[besti];             // ||q_r||^2 == w2[ind_r]
        }
    }
    if (lane == 0) atomicAdd(ws + WS_SQ2, q2);
    __syncthreads();

    // Coalesced q gather into ws: 8 iters of (8 rows x 32 float4)
    const int c4 = tid & 31, rg = tid >> 5;
    float4* wsq = (float4*)(ws + WS_Q);
    const float4* wv = (const float4*)W;
#pragma unroll
    for (int it = 0; it < 8; ++it) {
        int rr = it * 8 + rg;
        int idx = sidx[rr];
        wsq[(size_t)(r0 + rr) * 32 + c4] = wv[(size_t)idx * 32 + c4];
    }

    // Column sums of q over this block's 64 rows (L2-hot rows of W)
    const int d = tid & 127, g = tid >> 7;
    float s = 0.0f;
    for (int rr = g; rr < 64; rr += 2) s += W[(size_t)sidx[rr] * 128 + d];
    sh[g][d] = s;
    __syncthreads();
    if (g == 0) atomicAdd(ws + WS_SQ + d, sh[0][d] + sh[1][d]);
}

// quantized[i][j][:] = q[i]. 537 MB stream write; 8192 blocks x 64 KB.
// Block 0 additionally computes the loss scalar first (from precomputed
// sq/Sq2/x2/sx). Byte-identical to the 638 us round-0 kernel.
__global__ __launch_bounds__(256) void k_bcast(float* __restrict__ out,
                                               const float* __restrict__ ws) {
    const int bid = blockIdx.x, tid = threadIdx.x;
    if (bid == 0) {
        __shared__ float sh[256];
        float dotv = (tid < 128) ? ws[WS_SX + tid] * ws[WS_SQ + tid] : 0.0f;
        float sx2 = 0.0f;
        for (int r = tid; r < 1024; r += 256) sx2 += ws[WS_X2 + r];
        sh[tid] = dotv;
        __syncthreads();
        for (int s = 128; s > 0; s >>= 1) {
            if (tid < s) sh[tid] += sh[tid + s];
            __syncthreads();
        }
        const float dot = sh[0];
        __syncthreads();
        sh[tid] = sx2;
        __syncthreads();
        for (int s = 128; s > 0; s >>= 1) {
            if (tid < s) sh[tid] += sh[tid + s];
            __syncthreads();
        }
        if (tid == 0) {
            double Sx2 = (double)sh[0], Sq2 = (double)ws[WS_SQ2];
            double loss = 1.25 * (1024.0 * Sx2 + 1024.0 * Sq2 - 2.0 * (double)dot) / 134217728.0;
            out[LOSS_OFF] = (float)loss;
        }
        __syncthreads();
    }
    const int i = bid >> 3;          // row 0..1023
    const int e = bid & 7;           // eighth of the j range
    const int t = tid & 31;
    const vfloat4* src = (const vfloat4*)(ws + WS_Q) + (size_t)i * 32;
    vfloat4 qv = src[t];
    vfloat4* dst = (vfloat4*)out + (size_t)i * 32768 + t;
    const int jend = e * 128 + 128;
    for (int j = e * 128 + (tid >> 5); j < jend; j += 8) {
        dst[(size_t)j * 32] = qv;
    }
}

extern "C" void kernel_launch(void* const* d_in, const int* in_sizes, int n_in,
                              void* d_out, int out_size, void* d_ws, size_t ws_size,
                              hipStream_t stream) {
    const float* x = (const float*)d_in[0]; // 1024 x 128
    const float* W = (const float*)d_in[1]; // 8192 x 128
    float* out = (float*)d_out;
    float* ws = (float*)d_ws;

    hipLaunchKernelGGL(k_prep, dim3(40), dim3(256), 0, stream, x, W, ws);
    hipLaunchKernelGGL(k_score, dim3(64, 8), dim3(256), 0, stream, x, W,
                       ws + WS_W2, ws + WS_X2, ws + WS_PVAL, (int*)(ws + WS_PIDX));
    hipLaunchKernelGGL(k_argmin, dim3(16), dim3(256), 0, stream, W, ws + WS_W2,
                       ws + WS_PVAL, (const int*)(ws + WS_PIDX), out, ws);
    hipLaunchKernelGGL(k_bcast, dim3(8192), dim3(256), 0, stream, out, ws);
}